// Round 1
// baseline (126.478 us; speedup 1.0000x reference)
//
#include <hip/hip_runtime.h>
#include <hip/hip_bf16.h>

// GMM NLL: N=524288 rows, P=16, G=8.
// Strategy:
//  1) gmm_prep (1 block, 128 thr = 8 groups x 16 lanes):
//     Cholesky S_g = L L^T, V_g = L^{-1} (lower-tri, upper zero-padded),
//     logdet_g = 2*sum(log Lii), softmax(w) folded into per-group log-coef.
//     Results in d_ws:  V[8][16][16] | lcoef[8] | lam[16] | lam-1[16] | 1/lam[16]
//  2) gmm_main: one row per thread. quad_g = ||V_g (Xt - mu_g)||^2 using
//     LDS-broadcast float4 reads of V (conflict-free). mixed = sum_g
//     exp(-0.5*quad + lcoef_g + jac); block-reduce -log(mixed) -> atomicAdd.

#define P 16
#define G 8

__global__ __launch_bounds__(128) void gmm_prep(const float* __restrict__ lambdas,
                                                const float* __restrict__ sigmas,
                                                const float* __restrict__ w,
                                                float* __restrict__ ws) {
    __shared__ float Lsh[G][P][P];
    __shared__ float ldet[G];
    const int tid = threadIdx.x;
    const int g = tid >> 4;      // group 0..7
    const int r = tid & 15;      // row / column index within group

    // each thread holds its row of Sigma_g and builds its row of L
    float Srow[P], Lrow[P];
#pragma unroll
    for (int j = 0; j < P; ++j) Srow[j] = sigmas[g * P * P + r * P + j];

#pragma unroll
    for (int j = 0; j < P; ++j) {
        float s = Srow[j];
#pragma unroll
        for (int k = 0; k < P; ++k) {
            if (k < j) s -= Lrow[k] * Lsh[g][j][k];
        }
        if (r == j) {
            float dv = sqrtf(s);
            Lrow[j] = dv;
            Lsh[g][j][j] = dv;
        }
        __syncthreads();
        if (r > j) {
            float dv = s / Lsh[g][j][j];
            Lrow[j] = dv;
            Lsh[g][r][j] = dv;
        }
        __syncthreads();
    }

    if (r == 0) {
        float ld = 0.f;
#pragma unroll
        for (int j = 0; j < P; ++j) ld += __logf(Lsh[g][j][j]);
        ldet[g] = 2.0f * ld;
    }

    // invert L: thread r computes column r of V = L^{-1} (col[i]=0 for i<r)
    float col[P];
#pragma unroll
    for (int i = 0; i < P; ++i) {
        float s = 0.f;
#pragma unroll
        for (int k = 0; k < P; ++k) {
            if (k < i) s += Lsh[g][i][k] * col[k];
        }
        float rii = 1.0f / Lsh[g][i][i];
        col[i] = (i == r) ? rii : -s * rii;
    }
#pragma unroll
    for (int i = 0; i < P; ++i) ws[g * P * P + i * P + r] = col[i];

    __syncthreads();

    if (tid == 0) {
        // softmax over w -> log-weights, fold in lead and logdet
        float wm = w[0];
#pragma unroll
        for (int k = 1; k < G; ++k) wm = fmaxf(wm, w[k]);
        float s = 0.f;
#pragma unroll
        for (int k = 0; k < G; ++k) s += __expf(w[k] - wm);
        const float lse = wm + __logf(s);
        const float lead = -14.7030165f; // -0.5 * 16 * ln(2*pi)
#pragma unroll
        for (int k = 0; k < G; ++k)
            ws[G * P * P + k] = (w[k] - lse) + lead - 0.5f * ldet[k];
    }
    if (tid < P) {
        float lam = lambdas[tid];
        ws[G * P * P + G + tid]          = lam;
        ws[G * P * P + G + P + tid]      = lam - 1.0f;
        ws[G * P * P + G + 2 * P + tid]  = 1.0f / lam;
    }
}

__global__ __launch_bounds__(256) void gmm_main(const float* __restrict__ X,
                                                const float* __restrict__ mus,
                                                const float* __restrict__ ws,
                                                float* __restrict__ out,
                                                int nrows) {
    __shared__ __align__(16) float sV[G * P * P];
    __shared__ float smu[G * P];
    __shared__ float slc[G];
    __shared__ float slam[P], slm1[P], srl[P];
    __shared__ float red[4];

    const int tid = threadIdx.x;
    for (int i = tid; i < G * P * P; i += 256) sV[i] = ws[i];
    if (tid < G * P) smu[tid] = mus[tid];
    if (tid < G) slc[tid] = ws[G * P * P + tid];
    if (tid < P) {
        slam[tid] = ws[G * P * P + G + tid];
        slm1[tid] = ws[G * P * P + G + P + tid];
        srl[tid]  = ws[G * P * P + G + 2 * P + tid];
    }
    __syncthreads();

    const int n = blockIdx.x * 256 + tid;
    float nll = 0.f;
    if (n < nrows) {
        const float4* Xv = (const float4*)(X + (size_t)n * P);
        float4 q0 = Xv[0], q1 = Xv[1], q2 = Xv[2], q3 = Xv[3];
        float x[P] = {q0.x, q0.y, q0.z, q0.w, q1.x, q1.y, q1.z, q1.w,
                      q2.x, q2.y, q2.z, q2.w, q3.x, q3.y, q3.z, q3.w};
        float xt[P];
        float jac = 0.f;
#pragma unroll
        for (int p = 0; p < P; ++p) {
            float ln = __logf(x[p]);
            xt[p] = (__expf(slam[p] * ln) - 1.0f) * srl[p];
            jac = fmaf(ln, slm1[p], jac);
        }

        float mixed = 0.f;
        for (int g = 0; g < G; ++g) {
            const float* Vg = &sV[g * P * P];
            const float* mg = &smu[g * P];
            float d[P];
#pragma unroll
            for (int p = 0; p < P; ++p) d[p] = xt[p] - mg[p];
            float quad = 0.f;
#pragma unroll
            for (int p = 0; p < P; ++p) {
                float y = 0.f;
#pragma unroll
                for (int q4 = 0; q4 <= p / 4; ++q4) {
                    const float4 v4 = *(const float4*)(Vg + p * P + q4 * 4);
                    y = fmaf(v4.x, d[q4 * 4 + 0], y);
                    y = fmaf(v4.y, d[q4 * 4 + 1], y);
                    y = fmaf(v4.z, d[q4 * 4 + 2], y);
                    y = fmaf(v4.w, d[q4 * 4 + 3], y);
                }
                quad = fmaf(y, y, quad);
            }
            mixed += __expf(fmaf(-0.5f, quad, slc[g] + jac));
        }
        nll = -__logf(mixed);
    }

    // wave reduce (64 lanes) then block reduce then one atomic
#pragma unroll
    for (int off = 32; off > 0; off >>= 1) nll += __shfl_down(nll, off, 64);
    if ((tid & 63) == 0) red[tid >> 6] = nll;
    __syncthreads();
    if (tid == 0) atomicAdd(out, red[0] + red[1] + red[2] + red[3]);
}

extern "C" void kernel_launch(void* const* d_in, const int* in_sizes, int n_in,
                              void* d_out, int out_size, void* d_ws, size_t ws_size,
                              hipStream_t stream) {
    const float* X       = (const float*)d_in[0];
    const float* lambdas = (const float*)d_in[1];
    const float* mus     = (const float*)d_in[2];
    const float* sigmas  = (const float*)d_in[3];
    const float* w       = (const float*)d_in[4];
    float* out = (float*)d_out;
    float* ws  = (float*)d_ws;

    const int nrows = in_sizes[0] / P;   // 524288

    hipMemsetAsync(d_out, 0, sizeof(float), stream);
    gmm_prep<<<1, 128, 0, stream>>>(lambdas, sigmas, w, ws);
    gmm_main<<<(nrows + 255) / 256, 256, 0, stream>>>(X, mus, ws, out, nrows);
}

// Round 2
// 113.828 us; speedup vs baseline: 1.1111x; 1.1111x over previous
//
#include <hip/hip_runtime.h>
#include <hip/hip_bf16.h>

// GMM NLL: N=524288 rows, P=16, G=8.
// R2: replace LDS-broadcast quad (ds_read-issue-bound, 51us model == 48.5us
// measured) with bf16 MFMA 16x16x32 per group using homogeneous coordinates:
//   A_g = [ V_g (16x16) | -u_g | 0 ]  (16x32, bf16, u_g = V_g mu_g)
//   B   = [ xt ; 1 ; 0 ]              (32x16, bf16, 16 rows per tile)
//   Z = A_g B = V_g (xt - mu_g);  quad = sum_i Z_i^2  (fp32 accum)
// Per wave (64 rows = 4 tiles): 32 MFMA + ~6 ds ops vs 20480 ds ops before.

#define P 16
#define G 8

typedef short bf16x8 __attribute__((ext_vector_type(8)));   // 8 bf16 in 4 VGPRs
typedef float f32x4 __attribute__((ext_vector_type(4)));

__device__ __forceinline__ unsigned short f2bf(float f) {
    union { float f; unsigned u; } c; c.f = f;
    unsigned u = c.u;
    return (unsigned short)((u + 0x7FFFu + ((u >> 16) & 1u)) >> 16);  // RNE
}

// ws float layout:
//   [0, 2048)    : A-frags as ushort[8 groups][64 lanes][8]  (8 KB)
//   [2048, 2056) : lcoef[G]   (log softmax(w) + lead - 0.5*logdet)
//   [2056, 2072) : lam[P]
//   [2072, 2088) : lam-1[P]
//   [2088, 2104) : 1/lam[P]
#define WS_LC   2048
#define WS_LAM  2056
#define WS_LM1  2072
#define WS_RL   2088

__global__ __launch_bounds__(128) void gmm_prep(const float* __restrict__ lambdas,
                                                const float* __restrict__ mus,
                                                const float* __restrict__ sigmas,
                                                const float* __restrict__ w,
                                                float* __restrict__ ws,
                                                float* __restrict__ out) {
    __shared__ float Lsh[G][P][P];
    __shared__ float Vsh[G][P][P];
    __shared__ float ldet[G];
    const int tid = threadIdx.x;
    const int g = tid >> 4;
    const int r = tid & 15;

    float Srow[P], Lrow[P];
#pragma unroll
    for (int j = 0; j < P; ++j) Srow[j] = sigmas[g * P * P + r * P + j];

#pragma unroll
    for (int j = 0; j < P; ++j) {
        float s = Srow[j];
#pragma unroll
        for (int k = 0; k < P; ++k) {
            if (k < j) s -= Lrow[k] * Lsh[g][j][k];
        }
        if (r == j) {
            float dv = sqrtf(s);
            Lrow[j] = dv;
            Lsh[g][j][j] = dv;
        }
        __syncthreads();
        if (r > j) {
            float dv = s / Lsh[g][j][j];
            Lrow[j] = dv;
            Lsh[g][r][j] = dv;
        }
        __syncthreads();
    }

    if (r == 0) {
        float ld = 0.f;
#pragma unroll
        for (int j = 0; j < P; ++j) ld += __logf(Lsh[g][j][j]);
        ldet[g] = 2.0f * ld;
    }

    // invert L: thread r computes column r of V = L^{-1}
    float col[P];
#pragma unroll
    for (int i = 0; i < P; ++i) {
        float s = 0.f;
#pragma unroll
        for (int k = 0; k < P; ++k) {
            if (k < i) s += Lsh[g][i][k] * col[k];
        }
        float rii = 1.0f / Lsh[g][i][i];
        col[i] = (i == r) ? rii : -s * rii;
    }
#pragma unroll
    for (int i = 0; i < P; ++i) Vsh[g][i][r] = col[i];
    __syncthreads();

    // u_g[r] = (V_g mu_g)[r]
    float u = 0.f;
#pragma unroll
    for (int j = 0; j < P; ++j) u = fmaf(Vsh[g][r][j], mus[g * P + j], u);

    // A-fragments for mfma_f32_16x16x32_bf16:
    //   lane l: m = l&15 (=r), k = (l>>4)*8 + j
    //   quadrant 0: V[r][0..7], q1: V[r][8..15], q2: j==0 ? -u : 0, q3: 0
    unsigned short* ws16 = (unsigned short*)ws;
#pragma unroll
    for (int qq = 0; qq < 4; ++qq) {
        const int lane = qq * 16 + r;
#pragma unroll
        for (int j = 0; j < 8; ++j) {
            float val;
            if (qq == 0)      val = Vsh[g][r][j];
            else if (qq == 1) val = Vsh[g][r][8 + j];
            else if (qq == 2) val = (j == 0) ? -u : 0.f;
            else              val = 0.f;
            ws16[(g * 64 + lane) * 8 + j] = f2bf(val);
        }
    }

    if (tid == 0) {
        float wm = w[0];
#pragma unroll
        for (int k = 1; k < G; ++k) wm = fmaxf(wm, w[k]);
        float s = 0.f;
#pragma unroll
        for (int k = 0; k < G; ++k) s += __expf(w[k] - wm);
        const float lse = wm + __logf(s);
        const float lead = -14.7030165f; // -0.5 * 16 * ln(2*pi)
#pragma unroll
        for (int k = 0; k < G; ++k)
            ws[WS_LC + k] = (w[k] - lse) + lead - 0.5f * ldet[k];
        out[0] = 0.f;   // replaces the memset launch
    }
    if (tid < P) {
        float lam = lambdas[tid];
        ws[WS_LAM + tid] = lam;
        ws[WS_LM1 + tid] = lam - 1.0f;
        ws[WS_RL  + tid] = 1.0f / lam;
    }
}

__global__ __launch_bounds__(256) void gmm_main(const float* __restrict__ X,
                                                const float* __restrict__ ws,
                                                float* __restrict__ out,
                                                int nrows) {
    __shared__ __align__(16) unsigned short sxt[256 * 16];  // bf16 xt per row
    __shared__ float red[4];

    const int tid  = threadIdx.x;
    const int lane = tid & 63;
    const int wid  = tid >> 6;
    const int lq   = lane >> 4;           // quadrant 0..3
    const int ln15 = lane & 15;
    const unsigned short* ws16 = (const unsigned short*)ws;

    // resident A-fragments: 8 groups x 4 VGPRs
    bf16x8 afrag[G];
#pragma unroll
    for (int g = 0; g < G; ++g)
        afrag[g] = *(const bf16x8*)(ws16 + (g * 64 + lane) * 8);

    const int row = blockIdx.x * 256 + tid;
    const int rclamp = row < nrows ? row : nrows - 1;
    const float4* Xv = (const float4*)(X + (size_t)rclamp * P);
    float4 q0 = Xv[0], q1 = Xv[1], q2 = Xv[2], q3 = Xv[3];
    float xv[P] = {q0.x, q0.y, q0.z, q0.w, q1.x, q1.y, q1.z, q1.w,
                   q2.x, q2.y, q2.z, q2.w, q3.x, q3.y, q3.z, q3.w};

    float xt[P];
    float jac = 0.f;
#pragma unroll
    for (int p = 0; p < P; ++p) {
        float ln = __logf(xv[p]);
        xt[p] = (__expf(ws[WS_LAM + p] * ln) - 1.0f) * ws[WS_RL + p];
        jac = fmaf(ln, ws[WS_LM1 + p], jac);
    }

    // pack xt -> bf16, stage row (32 B) in LDS for B-fragment gathers
#pragma unroll
    for (int h = 0; h < 2; ++h) {
        union { unsigned u[4]; bf16x8 v; } c;
#pragma unroll
        for (int e = 0; e < 4; ++e)
            c.u[e] = (unsigned)f2bf(xt[h * 8 + e * 2]) |
                     ((unsigned)f2bf(xt[h * 8 + e * 2 + 1]) << 16);
        *(bf16x8*)(sxt + tid * 16 + h * 8) = c.v;
    }
    __syncthreads();

    // 4 tiles of 16 rows per wave; tile q covers rows wid*64 + q*16 + n
    float qsel[G];
#pragma unroll
    for (int q = 0; q < 4; ++q) {
        bf16x8 bfrag;
        if (lq < 2) {
            bfrag = *(const bf16x8*)(sxt + (wid * 64 + q * 16 + ln15) * 16 + lq * 8);
        } else {
            union { unsigned u[4]; bf16x8 v; } c;
            c.u[0] = (lq == 2) ? 0x3F80u : 0u;  // B[16][n] = 1.0 (homogeneous)
            c.u[1] = 0u; c.u[2] = 0u; c.u[3] = 0u;
            bfrag = c.v;
        }
#pragma unroll
        for (int g = 0; g < G; ++g) {
            f32x4 acc = {0.f, 0.f, 0.f, 0.f};
            acc = __builtin_amdgcn_mfma_f32_16x16x32_bf16(afrag[g], bfrag, acc, 0, 0, 0);
            // Z[i=lq*4+reg][n=ln15]; quad = sum_i Z^2 -> butterfly over quadrants
            float partial = acc[0] * acc[0];
            partial = fmaf(acc[1], acc[1], partial);
            partial = fmaf(acc[2], acc[2], partial);
            partial = fmaf(acc[3], acc[3], partial);
            float p1 = partial + __shfl_xor(partial, 16, 64);
            float qf = p1 + __shfl_xor(p1, 32, 64);
            // lane (wid,lane) owns global row wid*64+lane = tile lq, col ln15
            qsel[g] = (lq == q) ? qf : ((q == 0) ? 0.f : qsel[g]);
        }
    }

    float mixed = 0.f;
#pragma unroll
    for (int g = 0; g < G; ++g)
        mixed += __expf(fmaf(-0.5f, qsel[g], ws[WS_LC + g] + jac));

    float nll = (row < nrows) ? -__logf(mixed) : 0.f;

#pragma unroll
    for (int off = 32; off > 0; off >>= 1) nll += __shfl_down(nll, off, 64);
    if (lane == 0) red[wid] = nll;
    __syncthreads();
    if (tid == 0) atomicAdd(out, red[0] + red[1] + red[2] + red[3]);
}

extern "C" void kernel_launch(void* const* d_in, const int* in_sizes, int n_in,
                              void* d_out, int out_size, void* d_ws, size_t ws_size,
                              hipStream_t stream) {
    const float* X       = (const float*)d_in[0];
    const float* lambdas = (const float*)d_in[1];
    const float* mus     = (const float*)d_in[2];
    const float* sigmas  = (const float*)d_in[3];
    const float* w       = (const float*)d_in[4];
    float* out = (float*)d_out;
    float* ws  = (float*)d_ws;

    const int nrows = in_sizes[0] / P;   // 524288

    gmm_prep<<<1, 128, 0, stream>>>(lambdas, mus, sigmas, w, ws, out);
    gmm_main<<<(nrows + 255) / 256, 256, 0, stream>>>(X, ws, out, nrows);
}